// Round 1
// baseline (218.700 us; speedup 1.0000x reference)
//
#include <hip/hip_runtime.h>
#include <hip/hip_bf16.h>

#define BS   8
#define NREL 16
#define NN   512
#define EMB  256

typedef float f32x4 __attribute__((ext_vector_type(4)));
typedef short s16x8 __attribute__((ext_vector_type(8)));

// f32 -> bf16 bits, round-to-nearest-even
__device__ __forceinline__ unsigned short f2bf_bits(float f) {
    union { float f; unsigned u; } v; v.f = f;
    unsigned r = (v.u + 0x7FFFu + ((v.u >> 16) & 1u)) >> 16;
    return (unsigned short)r;
}

__device__ __forceinline__ float bf2f(unsigned short u) {
    union { unsigned u; float f; } v; v.u = ((unsigned)u) << 16;
    return v.f;
}

// ---------------------------------------------------------------------------
// K0: transpose W_r[16][256][256] + W_0[256][256] -> wT[17][h][d] bf16
// ---------------------------------------------------------------------------
__global__ __launch_bounds__(256) void k0_transpose(
        const float* __restrict__ Wr, const float* __restrict__ W0,
        unsigned short* __restrict__ wT) {
    __shared__ float tile[32][33];
    int bid = blockIdx.x;
    int rel = bid / 64;          // 0..16
    int t   = bid % 64;
    int d0  = (t & 7) * 32;
    int h0  = (t >> 3) * 32;
    int tx  = threadIdx.x & 31;
    int ty  = threadIdx.x >> 5;  // 0..7
    const float* src = (rel < NREL) ? (Wr + rel * (EMB * EMB)) : W0;
#pragma unroll
    for (int k = 0; k < 4; ++k) {
        int d = d0 + ty + k * 8;
        tile[ty + k * 8][tx] = src[d * EMB + h0 + tx];
    }
    __syncthreads();
#pragma unroll
    for (int k = 0; k < 4; ++k) {
        int h = h0 + ty + k * 8;
        wT[(rel * EMB + h) * EMB + d0 + tx] = f2bf_bits(tile[tx][ty + k * 8]);
    }
}

// ---------------------------------------------------------------------------
// K1: FW[b][rel][m][h] = sum_d F[b][m][d] * W[rel][d][h]
//   computed as D[h][m] = wT(A-op) x F(B-op), MFMA 16x16x32 bf16.
//   rel<16  -> FW  stored fragment-major: [(b*16+rel)*64 + m/8][h][m%8] bf16
//   rel==16 -> F2  stored fragment-major: [b*64 + m/8][h][m%8] bf16
// ---------------------------------------------------------------------------
__global__ __launch_bounds__(256) void k1_fw(
        const float* __restrict__ F, const unsigned short* __restrict__ wT,
        unsigned short* __restrict__ FW, unsigned short* __restrict__ F2) {
    int bid = blockIdx.x;
    int b   = bid & 7;
    int q   = bid >> 3;          // 0..135
    int rel = q % 17;
    int mt  = q / 17;            // 0..7
    int tid = threadIdx.x;
    int w   = tid >> 6;          // 0..3
    int l   = tid & 63;
    int lg  = l >> 4;            // 0..3
    int lr  = l & 15;

    int h0 = w * 64;             // wave's 64 h-rows (M-dim)
    int m0 = mt * 64;            // block's 64 m-cols (N-dim)

    const unsigned short* wt = wT + rel * (EMB * EMB);
    const float* Fb = F + (long)b * (NN * EMB);

    f32x4 acc[4][4];
#pragma unroll
    for (int i = 0; i < 4; ++i)
#pragma unroll
        for (int j = 0; j < 4; ++j) acc[i][j] = (f32x4){0.f, 0.f, 0.f, 0.f};

#pragma unroll 2
    for (int kk = 0; kk < EMB; kk += 32) {
        s16x8 afrag[4];
#pragma unroll
        for (int hi = 0; hi < 4; ++hi) {
            int row = h0 + hi * 16 + lr;
            afrag[hi] = *(const s16x8*)(wt + row * EMB + kk + lg * 8);
        }
        s16x8 bfrag[4];
#pragma unroll
        for (int bi = 0; bi < 4; ++bi) {
            int m = m0 + bi * 16 + lr;
            const float* p = Fb + m * EMB + kk + lg * 8;
            f32x4 x0 = *(const f32x4*)p;
            f32x4 x1 = *(const f32x4*)(p + 4);
            s16x8 v;
            v[0] = (short)f2bf_bits(x0[0]); v[1] = (short)f2bf_bits(x0[1]);
            v[2] = (short)f2bf_bits(x0[2]); v[3] = (short)f2bf_bits(x0[3]);
            v[4] = (short)f2bf_bits(x1[0]); v[5] = (short)f2bf_bits(x1[1]);
            v[6] = (short)f2bf_bits(x1[2]); v[7] = (short)f2bf_bits(x1[3]);
            bfrag[bi] = v;
        }
#pragma unroll
        for (int hi = 0; hi < 4; ++hi)
#pragma unroll
            for (int bi = 0; bi < 4; ++bi)
                acc[hi][bi] = __builtin_amdgcn_mfma_f32_16x16x32_bf16(
                    afrag[hi], bfrag[bi], acc[hi][bi], 0, 0, 0);
    }

    // Epilogue: D rows = h, cols = m.  C layout: col = lane&15, row = (lane>>4)*4+j
#pragma unroll
    for (int hi = 0; hi < 4; ++hi) {
#pragma unroll
        for (int bi = 0; bi < 4; ++bi) {
            int m  = m0 + bi * 16 + lr;
            int kg = m >> 3, ko = m & 7;
#pragma unroll
            for (int j = 0; j < 4; ++j) {
                int h = h0 + hi * 16 + lg * 4 + j;
                unsigned short vb = f2bf_bits(acc[hi][bi][j]);
                if (rel < NREL)
                    FW[(long)((b * 16 + rel) * 64 + kg) * 2048 + h * 8 + ko] = vb;
                else
                    F2[(long)(b * 64 + kg) * 2048 + h * 8 + ko] = vb;
            }
        }
    }
}

// ---------------------------------------------------------------------------
// K2: out[b][n][h] = relu( sum_r sum_m adj[b][r][n][m]*FW[b][r][m][h] + F2[b][n][h] )
//   grid 256 blocks: b = bid&7 (XCD-grouped), 16 m-tiles x 2 h-tiles
//   block 512 thr = 8 waves, wave tile 16 rows x 32 cols, K = 16*512
// ---------------------------------------------------------------------------
__global__ __launch_bounds__(512) void k2_main(
        const float* __restrict__ adj, const unsigned short* __restrict__ FW,
        const unsigned short* __restrict__ F2, float* __restrict__ out) {
    int bid = blockIdx.x;
    int b   = bid & 7;
    int t   = bid >> 3;          // 0..31
    int mt  = t & 15;            // 16 tiles of 32 rows
    int nt  = t >> 4;            // 0..1 (h halves)
    int tid = threadIdx.x;
    int w   = tid >> 6;          // 0..7
    int l   = tid & 63;
    int lg  = l >> 4, lr = l & 15;
    int wr  = w >> 2;            // 0..1
    int wc  = w & 3;             // 0..3

    int nrow = mt * 32 + wr * 16;     // wave's 16 output rows
    int h0   = nt * 128 + wc * 32;    // wave's 32 output cols

    f32x4 acc[2] = {{0.f,0.f,0.f,0.f},{0.f,0.f,0.f,0.f}};

    int arow = nrow + lr;
    const float* adj_b = adj + ((long)(b * 16) * NN + arow) * NN;
    const unsigned short* fw_b = FW + (long)(b * 16) * 131072;  // 64*2048 per (b,r)
    int col0 = (h0 + lr) * 8;

    for (int r = 0; r < NREL; ++r) {
        const float* pa = adj_b + (long)r * (NN * NN);
        const unsigned short* pb = fw_b + (long)r * 131072;
#pragma unroll 4
        for (int kk = 0; kk < NN; kk += 32) {
            f32x4 x0 = *(const f32x4*)(pa + kk + lg * 8);
            f32x4 x1 = *(const f32x4*)(pa + kk + lg * 8 + 4);
            s16x8 a;
            a[0] = (short)f2bf_bits(x0[0]); a[1] = (short)f2bf_bits(x0[1]);
            a[2] = (short)f2bf_bits(x0[2]); a[3] = (short)f2bf_bits(x0[3]);
            a[4] = (short)f2bf_bits(x1[0]); a[5] = (short)f2bf_bits(x1[1]);
            a[6] = (short)f2bf_bits(x1[2]); a[7] = (short)f2bf_bits(x1[3]);
            const unsigned short* pk = pb + ((kk >> 3) + lg) * 2048;
            s16x8 b0 = *(const s16x8*)(pk + col0);
            s16x8 b1 = *(const s16x8*)(pk + col0 + 128);   // +16 cols * 8
            acc[0] = __builtin_amdgcn_mfma_f32_16x16x32_bf16(a, b0, acc[0], 0, 0, 0);
            acc[1] = __builtin_amdgcn_mfma_f32_16x16x32_bf16(a, b1, acc[1], 0, 0, 0);
        }
    }

    // Epilogue: D rows = n (lg*4+j), cols = h (lr). Add F2, relu, store f32.
#pragma unroll
    for (int f = 0; f < 2; ++f) {
        int h = h0 + f * 16 + lr;
#pragma unroll
        for (int j = 0; j < 4; ++j) {
            int n = nrow + lg * 4 + j;
            float f2v = bf2f(F2[(long)(b * 64 + (n >> 3)) * 2048 + h * 8 + (n & 7)]);
            float v = acc[f][j] + f2v;
            out[((long)(b * NN + n)) * EMB + h] = v > 0.f ? v : 0.f;
        }
    }
}

// ---------------------------------------------------------------------------
extern "C" void kernel_launch(void* const* d_in, const int* in_sizes, int n_in,
                              void* d_out, int out_size, void* d_ws, size_t ws_size,
                              hipStream_t stream) {
    const float* F   = (const float*)d_in[0];   // [8][512][256]
    const float* adj = (const float*)d_in[1];   // [8][16][512][512]
    const float* Wr  = (const float*)d_in[2];   // [16][256][256]
    const float* W0  = (const float*)d_in[3];   // [256][256]
    float* out = (float*)d_out;                 // [8][512][256]

    unsigned short* wT = (unsigned short*)d_ws;          // 17*256*256 bf16
    unsigned short* FW = wT + 17 * 256 * 256;            // 8*16*64*2048 bf16
    unsigned short* F2 = FW + (long)8 * 16 * 64 * 2048;  // 8*64*2048 bf16

    k0_transpose<<<17 * 64, 256, 0, stream>>>(Wr, W0, wT);
    k1_fw<<<1088, 256, 0, stream>>>(F, wT, FW, F2);
    k2_main<<<256, 512, 0, stream>>>(adj, FW, F2, out);
}

// Round 2
// 159.847 us; speedup vs baseline: 1.3682x; 1.3682x over previous
//
#include <hip/hip_runtime.h>
#include <hip/hip_bf16.h>

#define BS   8
#define NREL 16
#define NN   512
#define EMB  256

typedef float f32x4 __attribute__((ext_vector_type(4)));
typedef short s16x8 __attribute__((ext_vector_type(8)));

// f32 -> bf16 bits, round-to-nearest-even
__device__ __forceinline__ unsigned short f2bf_bits(float f) {
    union { float f; unsigned u; } v; v.f = f;
    unsigned r = (v.u + 0x7FFFu + ((v.u >> 16) & 1u)) >> 16;
    return (unsigned short)r;
}

// ---------------------------------------------------------------------------
// K0: transpose W_r[16][256][256] + W_0[256][256] -> wT[17][h][d] bf16
// ---------------------------------------------------------------------------
__global__ __launch_bounds__(256) void k0_transpose(
        const float* __restrict__ Wr, const float* __restrict__ W0,
        unsigned short* __restrict__ wT) {
    __shared__ float tile[32][33];
    int bid = blockIdx.x;
    int rel = bid / 64;          // 0..16
    int t   = bid % 64;
    int d0  = (t & 7) * 32;
    int h0  = (t >> 3) * 32;
    int tx  = threadIdx.x & 31;
    int ty  = threadIdx.x >> 5;  // 0..7
    const float* src = (rel < NREL) ? (Wr + rel * (EMB * EMB)) : W0;
#pragma unroll
    for (int k = 0; k < 4; ++k) {
        int d = d0 + ty + k * 8;
        tile[ty + k * 8][tx] = src[d * EMB + h0 + tx];
    }
    __syncthreads();
#pragma unroll
    for (int k = 0; k < 4; ++k) {
        int h = h0 + ty + k * 8;
        wT[(rel * EMB + h) * EMB + d0 + tx] = f2bf_bits(tile[tx][ty + k * 8]);
    }
}

// ---------------------------------------------------------------------------
// K0b: convert F[8][512][256] f32 -> Fbf bf16 row-major
// ---------------------------------------------------------------------------
__global__ __launch_bounds__(256) void k0b_convF(
        const float* __restrict__ F, unsigned short* __restrict__ Fbf) {
    long i = ((long)blockIdx.x * 256 + threadIdx.x) * 8;
    f32x4 x0 = *(const f32x4*)(F + i);
    f32x4 x1 = *(const f32x4*)(F + i + 4);
    s16x8 v;
    v[0] = (short)f2bf_bits(x0[0]); v[1] = (short)f2bf_bits(x0[1]);
    v[2] = (short)f2bf_bits(x0[2]); v[3] = (short)f2bf_bits(x0[3]);
    v[4] = (short)f2bf_bits(x1[0]); v[5] = (short)f2bf_bits(x1[1]);
    v[6] = (short)f2bf_bits(x1[2]); v[7] = (short)f2bf_bits(x1[3]);
    *(s16x8*)(Fbf + i) = v;
}

// ---------------------------------------------------------------------------
// K1: FW[b][rel][m][h] = sum_d F[b][m][d] * W[rel][d][h]
//   D[h][m] = wT(A) x Fbf(B), MFMA 16x16x32 bf16, all-bf16 operand loads.
//   rel<16  -> FW fragment-major: [(b*16+rel)*64 + m/8][h][m%8] bf16
//   rel==16 -> F2f f32 row-major [b][n][h]
// ---------------------------------------------------------------------------
__global__ __launch_bounds__(256) void k1_fw(
        const unsigned short* __restrict__ Fbf, const unsigned short* __restrict__ wT,
        unsigned short* __restrict__ FW, float* __restrict__ F2f) {
    int bid = blockIdx.x;
    int b   = bid & 7;
    int q   = bid >> 3;          // 0..135
    int rel = q % 17;
    int mt  = q / 17;            // 0..7
    int tid = threadIdx.x;
    int w   = tid >> 6;          // 0..3
    int l   = tid & 63;
    int lg  = l >> 4;            // 0..3
    int lr  = l & 15;

    int h0 = w * 64;             // wave's 64 h-rows (M-dim)
    int m0 = mt * 64;            // block's 64 m-cols (N-dim)

    const unsigned short* wt = wT + rel * (EMB * EMB);
    const unsigned short* Fb = Fbf + (long)b * (NN * EMB);

    f32x4 acc[4][4];
#pragma unroll
    for (int i = 0; i < 4; ++i)
#pragma unroll
        for (int j = 0; j < 4; ++j) acc[i][j] = (f32x4){0.f, 0.f, 0.f, 0.f};

#pragma unroll 2
    for (int kk = 0; kk < EMB; kk += 32) {
        s16x8 afrag[4];
#pragma unroll
        for (int hi = 0; hi < 4; ++hi) {
            int row = h0 + hi * 16 + lr;
            afrag[hi] = *(const s16x8*)(wt + row * EMB + kk + lg * 8);
        }
        s16x8 bfrag[4];
#pragma unroll
        for (int bi = 0; bi < 4; ++bi) {
            int m = m0 + bi * 16 + lr;
            bfrag[bi] = *(const s16x8*)(Fb + m * EMB + kk + lg * 8);
        }
#pragma unroll
        for (int hi = 0; hi < 4; ++hi)
#pragma unroll
            for (int bi = 0; bi < 4; ++bi)
                acc[hi][bi] = __builtin_amdgcn_mfma_f32_16x16x32_bf16(
                    afrag[hi], bfrag[bi], acc[hi][bi], 0, 0, 0);
    }

    // Epilogue: D rows = h, cols = m.  C layout: col = lane&15, row = (lane>>4)*4+j
#pragma unroll
    for (int hi = 0; hi < 4; ++hi) {
#pragma unroll
        for (int bi = 0; bi < 4; ++bi) {
            int m  = m0 + bi * 16 + lr;
            int kg = m >> 3, ko = m & 7;
#pragma unroll
            for (int j = 0; j < 4; ++j) {
                int h = h0 + hi * 16 + lg * 4 + j;
                if (rel < NREL)
                    FW[(long)((b * 16 + rel) * 64 + kg) * 2048 + h * 8 + ko] =
                        f2bf_bits(acc[hi][bi][j]);
                else
                    F2f[((long)b * NN + m) * EMB + h] = acc[hi][bi][j];
            }
        }
    }
}

// ---------------------------------------------------------------------------
// K2: part[rg][b][n][h] = sum_{r in rg} sum_m adj[b][r][n][m]*FW[b][r][m][h]
//   grid 512 = 8b (XCD-grouped) x 16mt(32 rows) x 4rg(4 rels)
//   block 512 thr = 8 waves (2 wr x 4 wc), wave tile 16 rows x 64 cols, acc[4]
// ---------------------------------------------------------------------------
__global__ __launch_bounds__(512, 4) void k2_main(
        const float* __restrict__ adj, const unsigned short* __restrict__ FW,
        float* __restrict__ part) {
    int bid = blockIdx.x;
    int b   = bid & 7;
    int t   = bid >> 3;          // 0..63
    int mt  = t & 15;
    int rg  = t >> 4;            // 0..3
    int tid = threadIdx.x;
    int w   = tid >> 6;          // 0..7
    int l   = tid & 63;
    int lg  = l >> 4, lr = l & 15;
    int wr  = w >> 2;            // 0..1
    int wc  = w & 3;             // 0..3

    int nrow = mt * 32 + wr * 16;     // wave's 16 output rows
    int h0   = wc * 64;               // wave's 64 output cols

    f32x4 acc[4];
#pragma unroll
    for (int i = 0; i < 4; ++i) acc[i] = (f32x4){0.f, 0.f, 0.f, 0.f};

    int arow = nrow + lr;
    const float* adj_b = adj + (((long)(b * 16 + rg * 4)) * NN + arow) * NN;
    const unsigned short* fw_b = FW + (long)(b * 16 + rg * 4) * 131072;
    int col0 = (h0 + lr) * 8;

    for (int r = 0; r < 4; ++r) {
        const float* pa = adj_b + (long)r * (NN * NN);
        const unsigned short* pb = fw_b + (long)r * 131072;
#pragma unroll 4
        for (int kk = 0; kk < NN; kk += 32) {
            f32x4 x0 = *(const f32x4*)(pa + kk + lg * 8);
            f32x4 x1 = *(const f32x4*)(pa + kk + lg * 8 + 4);
            s16x8 a;
            a[0] = (short)f2bf_bits(x0[0]); a[1] = (short)f2bf_bits(x0[1]);
            a[2] = (short)f2bf_bits(x0[2]); a[3] = (short)f2bf_bits(x0[3]);
            a[4] = (short)f2bf_bits(x1[0]); a[5] = (short)f2bf_bits(x1[1]);
            a[6] = (short)f2bf_bits(x1[2]); a[7] = (short)f2bf_bits(x1[3]);
            const unsigned short* pk = pb + ((kk >> 3) + lg) * 2048;
            s16x8 b0 = *(const s16x8*)(pk + col0);
            s16x8 b1 = *(const s16x8*)(pk + col0 + 128);
            s16x8 b2 = *(const s16x8*)(pk + col0 + 256);
            s16x8 b3 = *(const s16x8*)(pk + col0 + 384);
            acc[0] = __builtin_amdgcn_mfma_f32_16x16x32_bf16(a, b0, acc[0], 0, 0, 0);
            acc[1] = __builtin_amdgcn_mfma_f32_16x16x32_bf16(a, b1, acc[1], 0, 0, 0);
            acc[2] = __builtin_amdgcn_mfma_f32_16x16x32_bf16(a, b2, acc[2], 0, 0, 0);
            acc[3] = __builtin_amdgcn_mfma_f32_16x16x32_bf16(a, b3, acc[3], 0, 0, 0);
        }
    }

    // D rows = n (lg*4+j), cols = h (lr). Write f32 partials.
    float* pp = part + ((long)rg * BS + b) * (NN * EMB);
#pragma unroll
    for (int f = 0; f < 4; ++f) {
        int h = h0 + f * 16 + lr;
#pragma unroll
        for (int j = 0; j < 4; ++j) {
            int n = nrow + lg * 4 + j;
            pp[(long)n * EMB + h] = acc[f][j];
        }
    }
}

// ---------------------------------------------------------------------------
// K3: out = relu(sum_rg part[rg] + F2f), vectorized f32x4
// ---------------------------------------------------------------------------
__global__ __launch_bounds__(256) void k3_reduce(
        const float* __restrict__ part, const float* __restrict__ F2f,
        float* __restrict__ out) {
    const long PS = (long)BS * NN * EMB;   // 1,048,576 floats per rg slice
    long i = ((long)blockIdx.x * 256 + threadIdx.x) * 4;
    f32x4 s = *(const f32x4*)(part + i);
    s += *(const f32x4*)(part + i + PS);
    s += *(const f32x4*)(part + i + 2 * PS);
    s += *(const f32x4*)(part + i + 3 * PS);
    s += *(const f32x4*)(F2f + i);
    f32x4 r;
#pragma unroll
    for (int j = 0; j < 4; ++j) r[j] = s[j] > 0.f ? s[j] : 0.f;
    *(f32x4*)(out + i) = r;
}

// ---------------------------------------------------------------------------
extern "C" void kernel_launch(void* const* d_in, const int* in_sizes, int n_in,
                              void* d_out, int out_size, void* d_ws, size_t ws_size,
                              hipStream_t stream) {
    const float* F   = (const float*)d_in[0];   // [8][512][256]
    const float* adj = (const float*)d_in[1];   // [8][16][512][512]
    const float* Wr  = (const float*)d_in[2];   // [16][256][256]
    const float* W0  = (const float*)d_in[3];   // [256][256]
    float* out = (float*)d_out;                 // [8][512][256]

    unsigned short* wT  = (unsigned short*)d_ws;             // 17*256*256 bf16
    unsigned short* Fbf = wT + 17 * 256 * 256;               // 8*512*256 bf16
    unsigned short* FW  = Fbf + (long)8 * 512 * 256;         // 8*16*64*2048 bf16
    float* F2f  = (float*)(FW + (long)8 * 16 * 64 * 2048);   // 8*512*256 f32
    float* part = F2f + (long)8 * 512 * 256;                 // 4*8*512*256 f32

    k0_transpose<<<17 * 64, 256, 0, stream>>>(Wr, W0, wT);
    k0b_convF<<<512, 256, 0, stream>>>(F, Fbf);
    k1_fw<<<1088, 256, 0, stream>>>(Fbf, wT, FW, F2f);
    k2_main<<<512, 512, 0, stream>>>(adj, FW, part);
    k3_reduce<<<1024, 256, 0, stream>>>(part, F2f, out);
}